// Round 15
// baseline (762.556 us; speedup 1.0000x reference)
//
#include <hip/hip_runtime.h>
#include <hip/hip_bf16.h>

#define NN 16384
#define KNN 10
#define HD 128
#define NL 7
#define TM 8
#define EDG 80      // TM*KNN
#define NE (NN*KNN) // total edges
#define TPB 4       // tiles per block (edge kernel)

// per-layer bf16 weight layout offsets (elements), all [outcol][k] (= W^T rows)
#define W1E_OFF 0
#define W1D_OFF 16384
#define W2_OFF  32768
#define C1_OFF  49152
#define N1_OFF  65536    // [outcol][256]
#define N2_OFF  98304
#define WL_STRIDE 114688

typedef float fv4 __attribute__((ext_vector_type(4)));
typedef short bv8 __attribute__((ext_vector_type(8)));

static __device__ __forceinline__ unsigned short f2b(float f) {
  __hip_bfloat16 h = __float2bfloat16(f);
  return __builtin_bit_cast(unsigned short, h);
}
static __device__ __forceinline__ float b2f(unsigned short u) {
  unsigned int x = ((unsigned int)u) << 16;
  return __builtin_bit_cast(float, x);
}
static __device__ __forceinline__ unsigned int pk2(float lo, float hi) {
  unsigned int r;
  asm("v_cvt_pk_bf16_f32 %0, %1, %2" : "=v"(r) : "v"(lo), "v"(hi));
  return r;
}
static __device__ __forceinline__ float silu_f(float x) {
  return x * __builtin_amdgcn_rcpf(1.0f + __expf(-x));
}
#define MFMA(a,b,c) __builtin_amdgcn_mfma_f32_16x16x32_bf16((a),(b),(c),0,0,0)

// direct global->LDS 16B DMA (dest = wave-uniform base + lane*16)
#define GLOAD_LDS(gp, lp) \
  __builtin_amdgcn_global_load_lds((const __attribute__((address_space(1))) void*)(gp), \
                                   (__attribute__((address_space(3))) void*)(lp), 16, 0, 0)

// activation LDS layout: [row][128 col] shorts, col XOR'd by (row&7)<<3
static __device__ __forceinline__ int swz8(int row, int col) {
  return row * 128 + (col ^ ((row & 7) << 3));
}

// ---------------- weight prep: fp32 -> bf16 transposed [outcol][k] ----------------
__global__ void prep_kernel(const float* __restrict__ ew1, const float* __restrict__ ew2,
                            const float* __restrict__ cw1, const float* __restrict__ nw1,
                            const float* __restrict__ nw2, unsigned short* __restrict__ wt)
{
  int g = blockIdx.x * 256 + threadIdx.x;
  if (g >= NL * WL_STRIDE) return;
  int l = g / WL_STRIDE;
  int r = g % WL_STRIDE;
  float v;
  if (r < 16384) {                       // W1e
    int c = r >> 7, k = r & 127;
    v = ew1[(l*257 + 1 + k)*128 + c];
  } else if (r < 32768) {                // W1d
    int q = r - 16384; int c = q >> 7, k = q & 127;
    v = ew1[(l*257 + 129 + k)*128 + c];
  } else if (r < 49152) {                // W2
    int q = r - 32768; int c = q >> 7, k = q & 127;
    v = ew2[(l*128 + k)*128 + c];
  } else if (r < 65536) {                // C1
    int q = r - 49152; int c = q >> 7, k = q & 127;
    v = cw1[(l*128 + k)*128 + c];
  } else if (r < 98304) {                // N1 [c][k0..255]
    int q = r - 65536; int c = q >> 8, k = q & 255;
    v = nw1[(l*256 + k)*128 + c];
  } else {                               // N2
    int q = r - 98304; int c = q >> 7, k = q & 127;
    v = nw2[(l*128 + k)*128 + c];
  }
  wt[g] = f2b(v);
}

// ---------------- embedding_in (bf16 hh) + x init ----------------
__global__ void init_kernel(const float* __restrict__ h, const float* __restrict__ eiw,
                            const float* __restrict__ eib,
                            unsigned short* __restrict__ hhb, float* __restrict__ x)
{
  int g = blockIdx.x * 256 + threadIdx.x;   // 16384*128
  int n = g >> 7, c = g & 127;
  float acc = eib[c];
  #pragma unroll
  for (int j = 0; j < 8; ++j) acc += h[n*11 + 3 + j] * eiw[j*128 + c];
  hhb[g] = f2b(acc);
  if (c < 3) x[n*4 + c] = h[n*11 + c] * (1.0f/3330.0f);
  if (c == 3) x[n*4 + 3] = 0.f;
}

// ---------------- embedding_out (vectorized bf16 reads) ----------------
__global__ void out_kernel(const unsigned short* __restrict__ hhb, const float* __restrict__ x,
                           const float* __restrict__ ow, const float* __restrict__ ob,
                           float* __restrict__ out)
{
  __shared__ float sOW[131*4];
  int tid = threadIdx.x;
  for (int i = tid; i < 131*4; i += 256) sOW[i] = ow[i];
  __syncthreads();
  int g = blockIdx.x * 256 + tid;           // 16384*4
  int n = g >> 2, o = g & 3;
  float acc = ob[o];
  #pragma unroll
  for (int kk = 0; kk < 16; ++kk) {
    bv8 v = *(const bv8*)(hhb + n*128 + kk*8);
    #pragma unroll
    for (int j = 0; j < 8; ++j)
      acc += b2f((unsigned short)v[j]) * sOW[(kk*8 + j)*4 + o];
  }
  #pragma unroll
  for (int d = 0; d < 3; ++d) acc += x[n*4 + d] * sOW[(128 + d)*4 + o];
  out[g] = acc;
}

// A-frag (weight) slices for this wave's 32 out-channels
static __device__ __forceinline__ void load_w8(bv8* w, const unsigned short* __restrict__ W,
                                               int cwb, int lr, int lh) {
  #pragma unroll
  for (int ks = 0; ks < 4; ++ks) {
    w[ks]     = *(const bv8*)(W + (cwb      + lr)*128 + ks*32 + lh*8);
    w[4 + ks] = *(const bv8*)(W + (cwb + 16 + lr)*128 + ks*32 + lh*8);
  }
}

// stage one 8-node tile: gather DMA into dstbuf + diff/rad -> diffg & sRad
static __device__ __forceinline__ void stage_tile(
    const int* __restrict__ idxp, const unsigned short* __restrict__ hhbin,
    const float* __restrict__ xin, float* __restrict__ diffg,
    unsigned short* __restrict__ dstbuf, float* __restrict__ sRad,
    int node0t, int tid)
{
  #pragma unroll
  for (int it = 0; it < 5; ++it) {
    int q = tid + it*256;                 // 1280 = 80 rows x 16 chunks
    int e = q >> 4, cq = q & 15;
    int s = idxp[node0t*KNN + e];
    int csw = (cq ^ (e & 7)) << 3;
    GLOAD_LDS(hhbin + s*HD + csw, dstbuf + ((q & ~63) << 3));
  }
  if (tid < EDG) {
    int e = tid, n = e / KNN;
    int s = idxp[node0t*KNN + e];
    fv4 xs4 = *(const fv4*)(xin + s*4);
    fv4 xd4 = *(const fv4*)(xin + (node0t+n)*4);
    float d0 = xs4[0]-xd4[0], d1 = xs4[1]-xd4[1], d2 = xs4[2]-xd4[2];
    float rad = d0*d0 + d1*d1 + d2*d2;
    sRad[e] = rad;
    fv4 dv = (fv4){d0, d1, d2, rad};
    *(fv4*)(diffg + (node0t*KNN + e)*4) = dv;
  }
}

// hc = W1d^T @ hh_dst + b1 -> sHC (wave-local cols, register inputs)
static __device__ __forceinline__ void hc_tile(
    const unsigned short* __restrict__ hhbin, const bv8* wd,
    fv4 hcb0, fv4 hcb1, float* __restrict__ sHC,
    int node0t, int lr, int lh, int cb0)
{
  bv8 hb[4];
  #pragma unroll
  for (int ks = 0; ks < 4; ++ks)
    hb[ks] = *(const bv8*)(hhbin + (node0t + (lr & 7))*HD + ks*32 + lh*8);
  fv4 hac0 = hcb0, hac1 = hcb1;
  #pragma unroll
  for (int ks = 0; ks < 4; ++ks) {
    hac0 = MFMA(wd[ks],   hb[ks], hac0);
    hac1 = MFMA(wd[4+ks], hb[ks], hac1);
  }
  if (lr < TM) {
    *(fv4*)(sHC + lr*132 + cb0)      = hac0;
    *(fv4*)(sHC + lr*132 + cb0 + 16) = hac1;
  }
}

// ---------------- edge kernel: 4 tiles/block, cross-tile staging prefetch ----------------
__global__ __launch_bounds__(256, 3) void edge_kernel(
    const int* __restrict__ idxp,
    const unsigned short* __restrict__ wt,
    const float* __restrict__ eb1, const float* __restrict__ eb2,
    const float* __restrict__ cb1, const float* __restrict__ cw2,
    const float* __restrict__ w1r0p,
    const unsigned short* __restrict__ hhbin,
    const float* __restrict__ xin,
    unsigned short* __restrict__ aggg,   // [NN][128] bf16 sum_ef
    float* __restrict__ diffg,           // [NE][4]  (dx,dy,dz,rad)
    float* __restrict__ cmPg)            // [4][NE]  per-wave cm partials
{
  __shared__ __align__(16) unsigned char smem[45504];
  unsigned short* bufA = (unsigned short*)(smem);           // [80][128]
  unsigned short* bufB = (unsigned short*)(smem + 20480);   // [80][128]
  float*          sHC  = (float*)(smem + 40960);            // [8][132] fp32 hc
  float*          sRad = (float*)(smem + 45184);            // [80]

  const int tid  = threadIdx.x;
  const int wave = tid >> 6;
  const int lane = tid & 63;
  const int lr   = lane & 15;
  const int lh   = lane >> 4;
  const int cwb  = wave * 32;
  const int cb0  = cwb + lh*4;
  const int node0 = blockIdx.x * (TM * TPB);

  // ---- block-persistent loads ----
  bv8 wd[8]; load_w8(wd, wt + W1D_OFF, cwb, lr, lh);
  fv4 cw2v0 = *(const fv4*)(cw2 + cb0);
  fv4 cw2v1 = *(const fv4*)(cw2 + cb0 + 16);
  fv4 w1r0v0 = *(const fv4*)(w1r0p + cb0);
  fv4 w1r0v1 = *(const fv4*)(w1r0p + cb0 + 16);
  fv4 hcb0 = *(const fv4*)(eb1 + cb0);
  fv4 hcb1 = *(const fv4*)(eb1 + cb0 + 16);

  // ---- prologue: stage tile 0 into bufA + hc(0) ----
  stage_tile(idxp, hhbin, xin, diffg, bufA, sRad, node0, tid);
  hc_tile(hhbin, wd, hcb0, hcb1, sHC, node0, lr, lh, cb0);
  bv8 we[8]; load_w8(we, wt + W1E_OFF, cwb, lr, lh);   // persistent, in flight across B
  __syncthreads();                                      // drains tile-0 gather DMA

  unsigned short* G = bufA;   // gather -> ef buffer
  unsigned short* O = bufB;   // t1 buffer / next-tile gather dest

  for (int t = 0; t < TPB; ++t) {
    const int node0t = node0 + t*TM;

    // ---- G1: t1 = silu(W1e^T@hh_src + hc + rad*w1r0): read G -> write O ; prefetch W2 ----
    bv8 w2r[8]; load_w8(w2r, wt + W2_OFF, cwb, lr, lh);
    {
      fv4 acc[5][2];
      #pragma unroll
      for (int n = 0; n < 5; ++n) {
        int e = n*16 + lr;
        int nd = e / KNN;
        float rad = sRad[e];
        fv4 h0 = *(const fv4*)(sHC + nd*132 + cb0);
        fv4 h1 = *(const fv4*)(sHC + nd*132 + cb0 + 16);
        acc[n][0] = h0 + w1r0v0*rad;
        acc[n][1] = h1 + w1r0v1*rad;
      }
      __builtin_amdgcn_s_setprio(1);
      #pragma unroll
      for (int ks = 0; ks < 4; ++ks) {
        #pragma unroll
        for (int n = 0; n < 5; ++n) {
          bv8 b = *(const bv8*)(G + swz8(n*16 + lr, ks*32 + lh*8));
          acc[n][0] = MFMA(we[ks],   b, acc[n][0]);
          acc[n][1] = MFMA(we[4+ks], b, acc[n][1]);
        }
      }
      __builtin_amdgcn_s_setprio(0);
      #pragma unroll
      for (int n = 0; n < 5; ++n) {
        int e = n*16 + lr;
        #pragma unroll
        for (int mt = 0; mt < 2; ++mt) {
          uint2 p;
          p.x = pk2(silu_f(acc[n][mt][0]), silu_f(acc[n][mt][1]));
          p.y = pk2(silu_f(acc[n][mt][2]), silu_f(acc[n][mt][3]));
          *(uint2*)(O + swz8(e, cb0 + mt*16)) = p;
        }
      }
    }
    __syncthreads();

    // ---- G2: ef = silu(W2^T @ t1 + b2): read O -> write G ; prefetch C1 ----
    bv8 c1r[8]; load_w8(c1r, wt + C1_OFF, cwb, lr, lh);
    {
      fv4 bb0 = *(const fv4*)(eb2 + cb0);
      fv4 bb1 = *(const fv4*)(eb2 + cb0 + 16);
      fv4 acc2[5][2];
      #pragma unroll
      for (int n = 0; n < 5; ++n) { acc2[n][0] = bb0; acc2[n][1] = bb1; }
      __builtin_amdgcn_s_setprio(1);
      #pragma unroll
      for (int ks = 0; ks < 4; ++ks) {
        #pragma unroll
        for (int n = 0; n < 5; ++n) {
          bv8 b = *(const bv8*)(O + swz8(n*16 + lr, ks*32 + lh*8));
          acc2[n][0] = MFMA(w2r[ks],   b, acc2[n][0]);
          acc2[n][1] = MFMA(w2r[4+ks], b, acc2[n][1]);
        }
      }
      __builtin_amdgcn_s_setprio(0);
      #pragma unroll
      for (int n = 0; n < 5; ++n) {
        int e = n*16 + lr;
        #pragma unroll
        for (int mt = 0; mt < 2; ++mt) {
          uint2 p;
          p.x = pk2(silu_f(acc2[n][mt][0]), silu_f(acc2[n][mt][1]));
          p.y = pk2(silu_f(acc2[n][mt][2]), silu_f(acc2[n][mt][3]));
          *(uint2*)(G + swz8(e, cb0 + mt*16)) = p;
        }
      }
    }
    __syncthreads();

    // ---- G3: c1 in-register from G(ef); cm -> cmPg; sum_ef -> aggg
    //      + prefetch next tile: gather DMA into O, diff, hc ----
    if (t + 1 < TPB)
      stage_tile(idxp, hhbin, xin, diffg, O, sRad, node0t + TM, tid);
    {
      fv4 bb0 = *(const fv4*)(cb1 + cb0);
      fv4 bb1 = *(const fv4*)(cb1 + cb0 + 16);
      fv4 acc3[5][2];
      #pragma unroll
      for (int n = 0; n < 5; ++n) { acc3[n][0] = bb0; acc3[n][1] = bb1; }
      __builtin_amdgcn_s_setprio(1);
      #pragma unroll
      for (int ks = 0; ks < 4; ++ks) {
        #pragma unroll
        for (int n = 0; n < 5; ++n) {
          bv8 b = *(const bv8*)(G + swz8(n*16 + lr, ks*32 + lh*8));
          acc3[n][0] = MFMA(c1r[ks],   b, acc3[n][0]);
          acc3[n][1] = MFMA(c1r[4+ks], b, acc3[n][1]);
        }
      }
      __builtin_amdgcn_s_setprio(0);
      // cm partials: silu + dot vs cw2 (fp32), reduce across lh, store per-wave
      #pragma unroll
      for (int n = 0; n < 5; ++n) {
        float pm = 0.f;
        #pragma unroll
        for (int j = 0; j < 4; ++j) {
          pm += silu_f(acc3[n][0][j]) * cw2v0[j];
          pm += silu_f(acc3[n][1][j]) * cw2v1[j];
        }
        pm += __shfl_xor(pm, 16);
        pm += __shfl_xor(pm, 32);
        if (lane < 16) cmPg[wave*NE + node0t*KNN + n*16 + lr] = pm;
      }
      // sum_ef on waves 2,3 -> global bf16
      if (tid >= 128) {
        int q = tid - 128;                  // 128 = 8 nodes x 16 chunks
        int n = q >> 4, c = (q & 15) << 3;
        float s[8] = {0,0,0,0,0,0,0,0};
        #pragma unroll
        for (int k = 0; k < KNN; ++k) {
          bv8 v = *(const bv8*)(G + swz8(n*KNN + k, c));
          #pragma unroll
          for (int e8 = 0; e8 < 8; ++e8) s[e8] += b2f((unsigned short)v[e8]);
        }
        uint4 pv = make_uint4(pk2(s[0], s[1]), pk2(s[2], s[3]),
                              pk2(s[4], s[5]), pk2(s[6], s[7]));
        *(uint4*)(aggg + (node0t + n)*HD + c) = pv;
      }
      if (t + 1 < TPB)
        hc_tile(hhbin, wd, hcb0, hcb1, sHC, node0t + TM, lr, lh, cb0);
    }
    __syncthreads();   // tile boundary: drains next-tile gather DMA

    // swap buffers
    unsigned short* tmp = G; G = O; O = tmp;
  }
}

// ---------------- node kernel: x-update + node MLP over 64 nodes/block ----------------
__global__ __launch_bounds__(256, 3) void node_kernel(
    const unsigned short* __restrict__ wt,
    const float* __restrict__ nb1, const float* __restrict__ nb2,
    const unsigned short* __restrict__ hhbin,
    const unsigned short* __restrict__ aggg,
    const float* __restrict__ diffg,
    const float* __restrict__ cmPg,
    const float* __restrict__ xin, float* __restrict__ xout,
    unsigned short* __restrict__ hhbout)
{
  __shared__ __align__(16) unsigned char smem[49152];
  unsigned short* sIn0 = (unsigned short*)(smem);           // [64][128] hh
  unsigned short* sIn1 = (unsigned short*)(smem + 16384);   // [64][128] sum_ef
  unsigned short* sN1  = (unsigned short*)(smem + 32768);   // [64][128] n1

  const int tid  = threadIdx.x;
  const int lane = tid & 63;
  const int wave = tid >> 6;
  const int lr   = lane & 15;
  const int lh   = lane >> 4;
  const int cwb  = wave * 32;
  const int cb0  = cwb + lh*4;
  const int node0 = blockIdx.x * 64;

  // ---- stage hh + sum_ef -> LDS via DMA (source-swizzled cols) ----
  #pragma unroll
  for (int it = 0; it < 4; ++it) {
    int q = tid + it*256;                 // 1024 = 64 rows x 16 chunks
    int r = q >> 4, cq = q & 15;
    int csw = (cq ^ (r & 7)) << 3;
    GLOAD_LDS(hhbin + (node0 + r)*HD + csw, sIn0 + ((q & ~63) << 3));
  }
  #pragma unroll
  for (int it = 0; it < 4; ++it) {
    int q = tid + it*256;
    int r = q >> 4, cq = q & 15;
    int csw = (cq ^ (r & 7)) << 3;
    GLOAD_LDS(aggg + (node0 + r)*HD + csw, sIn1 + ((q & ~63) << 3));
  }
  // ---- N1 weight prefetch (overlaps DMA) ----
  bv8 n1r[16];
  #pragma unroll
  for (int ks = 0; ks < 8; ++ks) {
    n1r[ks]     = *(const bv8*)(wt + N1_OFF + (cwb      + lr)*256 + ks*32 + lh*8);
    n1r[8 + ks] = *(const bv8*)(wt + N1_OFF + (cwb + 16 + lr)*256 + ks*32 + lh*8);
  }
  // ---- x-update (overlaps DMA; pure global reads) ----
  if (tid < 192) {
    int n = tid / 3, d = tid % 3;
    int e0 = (node0 + n)*KNN;
    float xo = xin[(node0+n)*4 + d];
    xo = fminf(fmaxf(xo, -1000.f), 1000.f);
    float s = 0.f;
    #pragma unroll
    for (int k = 0; k < KNN; ++k) {
      int e = e0 + k;
      float cm = cmPg[e] + cmPg[NE + e] + cmPg[2*NE + e] + cmPg[3*NE + e];
      float tr = diffg[e*4 + d] * cm;
      tr = fminf(fmaxf(tr, -1000.f), 1000.f);
      s += tr;
    }
    xout[(node0+n)*4 + d] = xo + s * (1.0f/KNN);
  }
  __syncthreads();                                      // B1 (drains DMA)

  // ---- nG1: n1 = silu(N1^T @ [hh | sum_ef] + nb1) -> sN1 ----
  {
    fv4 bb0 = *(const fv4*)(nb1 + cb0);
    fv4 bb1 = *(const fv4*)(nb1 + cb0 + 16);
    #pragma unroll
    for (int t = 0; t < 4; ++t) {
      fv4 acc0 = bb0, acc1 = bb1;
      #pragma unroll
      for (int ks = 0; ks < 4; ++ks) {
        bv8 b0 = *(const bv8*)(sIn0 + swz8(t*16 + lr, ks*32 + lh*8));
        bv8 b1 = *(const bv8*)(sIn1 + swz8(t*16 + lr, ks*32 + lh*8));
        acc0 = MFMA(n1r[ks],      b0, acc0);
        acc0 = MFMA(n1r[4+ks],    b1, acc0);
        acc1 = MFMA(n1r[8+ks],    b0, acc1);
        acc1 = MFMA(n1r[12+ks],   b1, acc1);
      }
      uint2 p0, p1;
      p0.x = pk2(silu_f(acc0[0]), silu_f(acc0[1]));
      p0.y = pk2(silu_f(acc0[2]), silu_f(acc0[3]));
      p1.x = pk2(silu_f(acc1[0]), silu_f(acc1[1]));
      p1.y = pk2(silu_f(acc1[2]), silu_f(acc1[3]));
      *(uint2*)(sN1 + swz8(t*16 + lr, cb0))      = p0;
      *(uint2*)(sN1 + swz8(t*16 + lr, cb0 + 16)) = p1;
    }
  }
  __syncthreads();                                      // B2

  // ---- nG2: hh_out = hh + N2^T @ n1 + nb2 -> hhbout ----
  {
    bv8 n2r[8]; load_w8(n2r, wt + N2_OFF, cwb, lr, lh);
    fv4 bb0 = *(const fv4*)(nb2 + cb0);
    fv4 bb1 = *(const fv4*)(nb2 + cb0 + 16);
    #pragma unroll
    for (int t = 0; t < 4; ++t) {
      fv4 acc0 = bb0, acc1 = bb1;
      #pragma unroll
      for (int ks = 0; ks < 4; ++ks) {
        bv8 b = *(const bv8*)(sN1 + swz8(t*16 + lr, ks*32 + lh*8));
        acc0 = MFMA(n2r[ks],   b, acc0);
        acc1 = MFMA(n2r[4+ks], b, acc1);
      }
      uint2 r0 = *(const uint2*)(sIn0 + swz8(t*16 + lr, cb0));
      uint2 r1 = *(const uint2*)(sIn0 + swz8(t*16 + lr, cb0 + 16));
      float v0 = b2f((unsigned short)(r0.x))       + acc0[0];
      float v1 = b2f((unsigned short)(r0.x >> 16)) + acc0[1];
      float v2 = b2f((unsigned short)(r0.y))       + acc0[2];
      float v3 = b2f((unsigned short)(r0.y >> 16)) + acc0[3];
      float w0 = b2f((unsigned short)(r1.x))       + acc1[0];
      float w1 = b2f((unsigned short)(r1.x >> 16)) + acc1[1];
      float w2 = b2f((unsigned short)(r1.y))       + acc1[2];
      float w3 = b2f((unsigned short)(r1.y >> 16)) + acc1[3];
      int g = (node0 + t*16 + lr)*HD + cb0;
      uint2 p;
      p.x = pk2(v0, v1); p.y = pk2(v2, v3);
      *(uint2*)(hhbout + g) = p;
      p.x = pk2(w0, w1); p.y = pk2(w2, w3);
      *(uint2*)(hhbout + g + 16) = p;
    }
  }
}

extern "C" void kernel_launch(void* const* d_in, const int* in_sizes, int n_in,
                              void* d_out, int out_size, void* d_ws, size_t ws_size,
                              hipStream_t stream)
{
  (void)in_sizes; (void)n_in; (void)out_size; (void)ws_size;
  const float* h   = (const float*)d_in[0];
  const int*   idx = (const int*)d_in[1];
  const float* eiw = (const float*)d_in[2];
  const float* eib = (const float*)d_in[3];
  const float* ew1 = (const float*)d_in[4];
  const float* eb1 = (const float*)d_in[5];
  const float* ew2 = (const float*)d_in[6];
  const float* eb2 = (const float*)d_in[7];
  const float* cw1 = (const float*)d_in[8];
  const float* cb1 = (const float*)d_in[9];
  const float* cw2 = (const float*)d_in[10];
  const float* nw1 = (const float*)d_in[11];
  const float* nb1 = (const float*)d_in[12];
  const float* nw2 = (const float*)d_in[13];
  const float* nb2 = (const float*)d_in[14];
  const float* eow = (const float*)d_in[15];
  const float* eob = (const float*)d_in[16];

  unsigned char* ws = (unsigned char*)d_ws;
  unsigned short* wt    = (unsigned short*)ws;                // 1,605,632 B
  unsigned short* hhbA  = (unsigned short*)(ws + 1605632);    // 4,194,304 B
  unsigned short* hhbB  = (unsigned short*)(ws + 5799936);    // 4,194,304 B
  float*          xA    = (float*)(ws + 9994240);             // 262,144 B
  float*          xB    = (float*)(ws + 10256384);            // 262,144 B
  unsigned short* aggg  = (unsigned short*)(ws + 10518528);   // 4,194,304 B
  float*          diffg = (float*)(ws + 14712832);            // 2,621,440 B
  float*          cmPg  = (float*)(ws + 17334272);            // 2,621,440 B

  prep_kernel<<<(NL*WL_STRIDE + 255)/256, 256, 0, stream>>>(ew1, ew2, cw1, nw1, nw2, wt);
  init_kernel<<<NN*HD/256, 256, 0, stream>>>(h, eiw, eib, hhbA, xA);

  unsigned short* hbs = hhbA; unsigned short* hbd = hhbB;
  float* xs = xA; float* xd = xB;
  for (int l = 0; l < NL; ++l) {
    edge_kernel<<<NN/(TM*TPB), 256, 0, stream>>>(idx, wt + (size_t)l*WL_STRIDE,
        eb1 + l*128, eb2 + l*128, cb1 + l*128, cw2 + l*128,
        ew1 + (size_t)l*257*128,
        hbs, xs, aggg, diffg, cmPg);
    node_kernel<<<NN/64, 256, 0, stream>>>(wt + (size_t)l*WL_STRIDE,
        nb1 + l*128, nb2 + l*128,
        hbs, aggg, diffg, cmPg, xs, xd, hbd);
    unsigned short* ht = hbs; hbs = hbd; hbd = ht;
    float* t = xs; xs = xd; xd = t;
  }
  out_kernel<<<NN*4/256, 256, 0, stream>>>(hbs, xs, eow, eob, (float*)d_out);
}

// Round 16
// 403.887 us; speedup vs baseline: 1.8880x; 1.8880x over previous
//
#include <hip/hip_runtime.h>
#include <hip/hip_bf16.h>

#define NN 16384
#define KNN 10
#define HD 128
#define NL 7
#define TM 8
#define EDG 80      // TM*KNN
#define NE (NN*KNN) // total edges

// per-layer bf16 weight layout offsets (elements), all [outcol][k] (= W^T rows)
#define W1E_OFF 0
#define W1D_OFF 16384
#define W2_OFF  32768
#define C1_OFF  49152
#define N1_OFF  65536    // [outcol][256]
#define N2_OFF  98304
#define WL_STRIDE 114688

typedef float fv4 __attribute__((ext_vector_type(4)));
typedef short bv8 __attribute__((ext_vector_type(8)));

static __device__ __forceinline__ unsigned short f2b(float f) {
  __hip_bfloat16 h = __float2bfloat16(f);
  return __builtin_bit_cast(unsigned short, h);
}
static __device__ __forceinline__ float b2f(unsigned short u) {
  unsigned int x = ((unsigned int)u) << 16;
  return __builtin_bit_cast(float, x);
}
static __device__ __forceinline__ unsigned int pk2(float lo, float hi) {
  unsigned int r;
  asm("v_cvt_pk_bf16_f32 %0, %1, %2" : "=v"(r) : "v"(lo), "v"(hi));
  return r;
}
static __device__ __forceinline__ float silu_f(float x) {
  return x * __builtin_amdgcn_rcpf(1.0f + __expf(-x));
}
#define MFMA(a,b,c) __builtin_amdgcn_mfma_f32_16x16x32_bf16((a),(b),(c),0,0,0)

// direct global->LDS 16B DMA (dest = wave-uniform base + lane*16)
#define GLOAD_LDS(gp, lp) \
  __builtin_amdgcn_global_load_lds((const __attribute__((address_space(1))) void*)(gp), \
                                   (__attribute__((address_space(3))) void*)(lp), 16, 0, 0)

// activation LDS layout: [row][128 col] shorts, col XOR'd by (row&7)<<3
static __device__ __forceinline__ int swz8(int row, int col) {
  return row * 128 + (col ^ ((row & 7) << 3));
}

// ---------------- weight prep: fp32 -> bf16 transposed [outcol][k] ----------------
__global__ void prep_kernel(const float* __restrict__ ew1, const float* __restrict__ ew2,
                            const float* __restrict__ cw1, const float* __restrict__ nw1,
                            const float* __restrict__ nw2, unsigned short* __restrict__ wt)
{
  int g = blockIdx.x * 256 + threadIdx.x;
  if (g >= NL * WL_STRIDE) return;
  int l = g / WL_STRIDE;
  int r = g % WL_STRIDE;
  float v;
  if (r < 16384) {                       // W1e
    int c = r >> 7, k = r & 127;
    v = ew1[(l*257 + 1 + k)*128 + c];
  } else if (r < 32768) {                // W1d
    int q = r - 16384; int c = q >> 7, k = q & 127;
    v = ew1[(l*257 + 129 + k)*128 + c];
  } else if (r < 49152) {                // W2
    int q = r - 32768; int c = q >> 7, k = q & 127;
    v = ew2[(l*128 + k)*128 + c];
  } else if (r < 65536) {                // C1
    int q = r - 49152; int c = q >> 7, k = q & 127;
    v = cw1[(l*128 + k)*128 + c];
  } else if (r < 98304) {                // N1 [c][k0..255]
    int q = r - 65536; int c = q >> 8, k = q & 255;
    v = nw1[(l*256 + k)*128 + c];
  } else {                               // N2
    int q = r - 98304; int c = q >> 7, k = q & 127;
    v = nw2[(l*128 + k)*128 + c];
  }
  wt[g] = f2b(v);
}

// ---------------- embedding_in (bf16 hh) + x init ----------------
__global__ void init_kernel(const float* __restrict__ h, const float* __restrict__ eiw,
                            const float* __restrict__ eib,
                            unsigned short* __restrict__ hhb, float* __restrict__ x)
{
  int g = blockIdx.x * 256 + threadIdx.x;   // 16384*128
  int n = g >> 7, c = g & 127;
  float acc = eib[c];
  #pragma unroll
  for (int j = 0; j < 8; ++j) acc += h[n*11 + 3 + j] * eiw[j*128 + c];
  hhb[g] = f2b(acc);
  if (c < 3) x[n*4 + c] = h[n*11 + c] * (1.0f/3330.0f);
  if (c == 3) x[n*4 + 3] = 0.f;
}

// ---------------- embedding_out (vectorized bf16 reads) ----------------
__global__ void out_kernel(const unsigned short* __restrict__ hhb, const float* __restrict__ x,
                           const float* __restrict__ ow, const float* __restrict__ ob,
                           float* __restrict__ out)
{
  __shared__ float sOW[131*4];
  int tid = threadIdx.x;
  for (int i = tid; i < 131*4; i += 256) sOW[i] = ow[i];
  __syncthreads();
  int g = blockIdx.x * 256 + tid;           // 16384*4
  int n = g >> 2, o = g & 3;
  float acc = ob[o];
  #pragma unroll
  for (int kk = 0; kk < 16; ++kk) {
    bv8 v = *(const bv8*)(hhb + n*128 + kk*8);
    #pragma unroll
    for (int j = 0; j < 8; ++j)
      acc += b2f((unsigned short)v[j]) * sOW[(kk*8 + j)*4 + o];
  }
  #pragma unroll
  for (int d = 0; d < 3; ++d) acc += x[n*4 + d] * sOW[(128 + d)*4 + o];
  out[g] = acc;
}

// A-frag (weight) slices for this wave's 32 out-channels
static __device__ __forceinline__ void load_w8(bv8* w, const unsigned short* __restrict__ W,
                                               int cwb, int lr, int lh) {
  #pragma unroll
  for (int ks = 0; ks < 4; ++ks) {
    w[ks]     = *(const bv8*)(W + (cwb      + lr)*128 + ks*32 + lh*8);
    w[4 + ks] = *(const bv8*)(W + (cwb + 16 + lr)*128 + ks*32 + lh*8);
  }
}

// ---------------- edge kernel: gather + edge MLP + coord head, 3 barriers ----------------
__global__ __launch_bounds__(256, 3) void edge_kernel(
    const int* __restrict__ idxp,
    const unsigned short* __restrict__ wt,
    const float* __restrict__ eb1, const float* __restrict__ eb2,
    const float* __restrict__ cb1, const float* __restrict__ cw2,
    const float* __restrict__ w1r0p,
    const unsigned short* __restrict__ hhbin,
    const float* __restrict__ xin,
    unsigned short* __restrict__ aggg,   // [NN][128] bf16 sum_ef
    float* __restrict__ diffg,           // [NE][4]  (dx,dy,dz,rad)
    float* __restrict__ cmPg)            // [4][NE]  per-wave cm partials
{
  __shared__ __align__(16) unsigned char smem[45504];
  unsigned short* sA   = (unsigned short*)(smem);           // [80][128] hh_src -> ef
  unsigned short* sB   = (unsigned short*)(smem + 20480);   // [80][128] t1
  float*          sHC  = (float*)(smem + 40960);            // [8][132] fp32 hc
  float*          sRad = (float*)(smem + 45184);            // [80]
  unsigned short* sEf = sA;

  const int tid  = threadIdx.x;
  const int wave = tid >> 6;
  const int lane = tid & 63;
  const int lr   = lane & 15;
  const int lh   = lane >> 4;
  const int cwb  = wave * 32;
  const int cb0  = cwb + lh*4;
  const int node0 = blockIdx.x * TM;

  // ---- async gather hh_src -> sA (source-swizzled cols) ----
  #pragma unroll
  for (int it = 0; it < 5; ++it) {
    int q = tid + it*256;                 // 1280 = 80 rows x 16 chunks
    int e = q >> 4, cq = q & 15;
    int s = idxp[node0*KNN + e];
    int csw = (cq ^ (e & 7)) << 3;
    GLOAD_LDS(hhbin + s*HD + csw, sA + ((q & ~63) << 3));
  }

  // ---- early register loads ----
  bv8 hb[4];
  #pragma unroll
  for (int ks = 0; ks < 4; ++ks)
    hb[ks] = *(const bv8*)(hhbin + (node0 + (lr & 7))*HD + ks*32 + lh*8);
  bv8 wd[8]; load_w8(wd, wt + W1D_OFF, cwb, lr, lh);
  fv4 cw2v0 = *(const fv4*)(cw2 + cb0);
  fv4 cw2v1 = *(const fv4*)(cw2 + cb0 + 16);
  fv4 w1r0v0 = *(const fv4*)(w1r0p + cb0);
  fv4 w1r0v1 = *(const fv4*)(w1r0p + cb0 + 16);

  // ---- diff/radial fp32 (+ diff to global for node kernel) ----
  if (tid < EDG) {
    int e = tid, n = e / KNN;
    int s = idxp[node0*KNN + e];
    fv4 xs4 = *(const fv4*)(xin + s*4);
    fv4 xd4 = *(const fv4*)(xin + (node0+n)*4);
    float d0 = xs4[0]-xd4[0], d1 = xs4[1]-xd4[1], d2 = xs4[2]-xd4[2];
    float rad = d0*d0 + d1*d1 + d2*d2;
    sRad[e] = rad;
    fv4 dv = (fv4){d0, d1, d2, rad};
    *(fv4*)(diffg + (node0*KNN + e)*4) = dv;
  }
  // ---- hc = W1d^T @ hh_dst + b1 (registers only; pre-barrier) ----
  {
    fv4 hac0 = *(const fv4*)(eb1 + cb0);
    fv4 hac1 = *(const fv4*)(eb1 + cb0 + 16);
    #pragma unroll
    for (int ks = 0; ks < 4; ++ks) {
      hac0 = MFMA(wd[ks],   hb[ks], hac0);
      hac1 = MFMA(wd[4+ks], hb[ks], hac1);
    }
    if (lr < TM) {
      *(fv4*)(sHC + lr*132 + cb0)      = hac0;
      *(fv4*)(sHC + lr*132 + cb0 + 16) = hac1;
    }
  }
  bv8 we[8]; load_w8(we, wt + W1E_OFF, cwb, lr, lh);
  __syncthreads();                                      // B1 (drains gather DMA)

  // ---- G1: t1 = silu(W1e^T@hh_src + hc + rad*w1r0) -> sB ; prefetch W2 ----
  bv8 w2r[8]; load_w8(w2r, wt + W2_OFF, cwb, lr, lh);
  {
    fv4 acc[5][2];
    #pragma unroll
    for (int n = 0; n < 5; ++n) {
      int e = n*16 + lr;
      int nd = e / KNN;
      float rad = sRad[e];
      fv4 h0 = *(const fv4*)(sHC + nd*132 + cb0);
      fv4 h1 = *(const fv4*)(sHC + nd*132 + cb0 + 16);
      acc[n][0] = h0 + w1r0v0*rad;
      acc[n][1] = h1 + w1r0v1*rad;
    }
    __builtin_amdgcn_s_setprio(1);
    #pragma unroll
    for (int ks = 0; ks < 4; ++ks) {
      #pragma unroll
      for (int n = 0; n < 5; ++n) {
        bv8 b = *(const bv8*)(sA + swz8(n*16 + lr, ks*32 + lh*8));
        acc[n][0] = MFMA(we[ks],   b, acc[n][0]);
        acc[n][1] = MFMA(we[4+ks], b, acc[n][1]);
      }
    }
    __builtin_amdgcn_s_setprio(0);
    #pragma unroll
    for (int n = 0; n < 5; ++n) {
      int e = n*16 + lr;
      #pragma unroll
      for (int mt = 0; mt < 2; ++mt) {
        uint2 p;
        p.x = pk2(silu_f(acc[n][mt][0]), silu_f(acc[n][mt][1]));
        p.y = pk2(silu_f(acc[n][mt][2]), silu_f(acc[n][mt][3]));
        *(uint2*)(sB + swz8(e, cb0 + mt*16)) = p;
      }
    }
  }
  __syncthreads();                                      // B2

  // ---- G2: ef = silu(W2^T @ t1 + b2) -> sA ; prefetch C1 + cb1 ----
  bv8 c1r[8]; load_w8(c1r, wt + C1_OFF, cwb, lr, lh);
  fv4 c1b0 = *(const fv4*)(cb1 + cb0);
  fv4 c1b1 = *(const fv4*)(cb1 + cb0 + 16);
  {
    fv4 bb0 = *(const fv4*)(eb2 + cb0);
    fv4 bb1 = *(const fv4*)(eb2 + cb0 + 16);
    fv4 acc[5][2];
    #pragma unroll
    for (int n = 0; n < 5; ++n) { acc[n][0] = bb0; acc[n][1] = bb1; }
    __builtin_amdgcn_s_setprio(1);
    #pragma unroll
    for (int ks = 0; ks < 4; ++ks) {
      #pragma unroll
      for (int n = 0; n < 5; ++n) {
        bv8 b = *(const bv8*)(sB + swz8(n*16 + lr, ks*32 + lh*8));
        acc[n][0] = MFMA(w2r[ks],   b, acc[n][0]);
        acc[n][1] = MFMA(w2r[4+ks], b, acc[n][1]);
      }
    }
    __builtin_amdgcn_s_setprio(0);
    #pragma unroll
    for (int n = 0; n < 5; ++n) {
      int e = n*16 + lr;
      #pragma unroll
      for (int mt = 0; mt < 2; ++mt) {
        uint2 p;
        p.x = pk2(silu_f(acc[n][mt][0]), silu_f(acc[n][mt][1]));
        p.y = pk2(silu_f(acc[n][mt][2]), silu_f(acc[n][mt][3]));
        *(uint2*)(sA + swz8(e, cb0 + mt*16)) = p;
      }
    }
  }
  __syncthreads();                                      // B3

  // ---- G3: c1 in-register; cm partials -> cmPg; waves 2,3: sum_ef -> aggg ----
  {
    fv4 acc[5][2];
    #pragma unroll
    for (int n = 0; n < 5; ++n) { acc[n][0] = c1b0; acc[n][1] = c1b1; }
    __builtin_amdgcn_s_setprio(1);
    #pragma unroll
    for (int ks = 0; ks < 4; ++ks) {
      #pragma unroll
      for (int n = 0; n < 5; ++n) {
        bv8 b = *(const bv8*)(sEf + swz8(n*16 + lr, ks*32 + lh*8));
        acc[n][0] = MFMA(c1r[ks],   b, acc[n][0]);
        acc[n][1] = MFMA(c1r[4+ks], b, acc[n][1]);
      }
    }
    __builtin_amdgcn_s_setprio(0);
    // cm partials: silu + dot vs cw2 (fp32), reduce across lh, store per-wave
    #pragma unroll
    for (int n = 0; n < 5; ++n) {
      float pm = 0.f;
      #pragma unroll
      for (int j = 0; j < 4; ++j) {
        pm += silu_f(acc[n][0][j]) * cw2v0[j];
        pm += silu_f(acc[n][1][j]) * cw2v1[j];
      }
      pm += __shfl_xor(pm, 16);
      pm += __shfl_xor(pm, 32);
      if (lane < 16) cmPg[wave*NE + node0*KNN + n*16 + lr] = pm;
    }
    // sum_ef on waves 2,3 -> global bf16 (linear layout for node-kernel DMA)
    if (tid >= 128) {
      int q = tid - 128;                  // 128 = 8 nodes x 16 chunks
      int n = q >> 4, c = (q & 15) << 3;
      float s[8] = {0,0,0,0,0,0,0,0};
      #pragma unroll
      for (int k = 0; k < KNN; ++k) {
        bv8 v = *(const bv8*)(sEf + swz8(n*KNN + k, c));
        #pragma unroll
        for (int e8 = 0; e8 < 8; ++e8) s[e8] += b2f((unsigned short)v[e8]);
      }
      uint4 pv = make_uint4(pk2(s[0], s[1]), pk2(s[2], s[3]),
                            pk2(s[4], s[5]), pk2(s[6], s[7]));
      *(uint4*)(aggg + (node0 + n)*HD + c) = pv;
    }
  }
}

// ---------------- node kernel: x-update + node MLP over 64 nodes/block ----------------
__global__ __launch_bounds__(256, 3) void node_kernel(
    const unsigned short* __restrict__ wt,
    const float* __restrict__ nb1, const float* __restrict__ nb2,
    const unsigned short* __restrict__ hhbin,
    const unsigned short* __restrict__ aggg,
    const float* __restrict__ diffg,
    const float* __restrict__ cmPg,
    const float* __restrict__ xin, float* __restrict__ xout,
    unsigned short* __restrict__ hhbout)
{
  __shared__ __align__(16) unsigned char smem[49152];
  unsigned short* sIn0 = (unsigned short*)(smem);           // [64][128] hh
  unsigned short* sIn1 = (unsigned short*)(smem + 16384);   // [64][128] sum_ef
  unsigned short* sN1  = (unsigned short*)(smem + 32768);   // [64][128] n1

  const int tid  = threadIdx.x;
  const int lane = tid & 63;
  const int wave = tid >> 6;
  const int lr   = lane & 15;
  const int lh   = lane >> 4;
  const int cwb  = wave * 32;
  const int cb0  = cwb + lh*4;
  const int node0 = blockIdx.x * 64;

  // ---- stage hh + sum_ef -> LDS via DMA (source-swizzled cols) ----
  #pragma unroll
  for (int it = 0; it < 4; ++it) {
    int q = tid + it*256;                 // 1024 = 64 rows x 16 chunks
    int r = q >> 4, cq = q & 15;
    int csw = (cq ^ (r & 7)) << 3;
    GLOAD_LDS(hhbin + (node0 + r)*HD + csw, sIn0 + ((q & ~63) << 3));
  }
  #pragma unroll
  for (int it = 0; it < 4; ++it) {
    int q = tid + it*256;
    int r = q >> 4, cq = q & 15;
    int csw = (cq ^ (r & 7)) << 3;
    GLOAD_LDS(aggg + (node0 + r)*HD + csw, sIn1 + ((q & ~63) << 3));
  }
  // ---- N1 weight prefetch (overlaps DMA) ----
  bv8 n1r[16];
  #pragma unroll
  for (int ks = 0; ks < 8; ++ks) {
    n1r[ks]     = *(const bv8*)(wt + N1_OFF + (cwb      + lr)*256 + ks*32 + lh*8);
    n1r[8 + ks] = *(const bv8*)(wt + N1_OFF + (cwb + 16 + lr)*256 + ks*32 + lh*8);
  }
  // ---- x-update (overlaps DMA; pure global reads) ----
  if (tid < 192) {
    int n = tid / 3, d = tid % 3;
    int e0 = (node0 + n)*KNN;
    float xo = xin[(node0+n)*4 + d];
    xo = fminf(fmaxf(xo, -1000.f), 1000.f);
    float s = 0.f;
    #pragma unroll
    for (int k = 0; k < KNN; ++k) {
      int e = e0 + k;
      float cm = cmPg[e] + cmPg[NE + e] + cmPg[2*NE + e] + cmPg[3*NE + e];
      float tr = diffg[e*4 + d] * cm;
      tr = fminf(fmaxf(tr, -1000.f), 1000.f);
      s += tr;
    }
    xout[(node0+n)*4 + d] = xo + s * (1.0f/KNN);
  }
  __syncthreads();                                      // B1 (drains DMA)

  // ---- nG1: n1 = silu(N1^T @ [hh | sum_ef] + nb1) -> sN1 ----
  {
    fv4 bb0 = *(const fv4*)(nb1 + cb0);
    fv4 bb1 = *(const fv4*)(nb1 + cb0 + 16);
    #pragma unroll
    for (int t = 0; t < 4; ++t) {
      fv4 acc0 = bb0, acc1 = bb1;
      #pragma unroll
      for (int ks = 0; ks < 4; ++ks) {
        bv8 b0 = *(const bv8*)(sIn0 + swz8(t*16 + lr, ks*32 + lh*8));
        bv8 b1 = *(const bv8*)(sIn1 + swz8(t*16 + lr, ks*32 + lh*8));
        acc0 = MFMA(n1r[ks],      b0, acc0);
        acc0 = MFMA(n1r[4+ks],    b1, acc0);
        acc1 = MFMA(n1r[8+ks],    b0, acc1);
        acc1 = MFMA(n1r[12+ks],   b1, acc1);
      }
      uint2 p0, p1;
      p0.x = pk2(silu_f(acc0[0]), silu_f(acc0[1]));
      p0.y = pk2(silu_f(acc0[2]), silu_f(acc0[3]));
      p1.x = pk2(silu_f(acc1[0]), silu_f(acc1[1]));
      p1.y = pk2(silu_f(acc1[2]), silu_f(acc1[3]));
      *(uint2*)(sN1 + swz8(t*16 + lr, cb0))      = p0;
      *(uint2*)(sN1 + swz8(t*16 + lr, cb0 + 16)) = p1;
    }
  }
  __syncthreads();                                      // B2

  // ---- nG2: hh_out = hh + N2^T @ n1 + nb2 -> hhbout ----
  {
    bv8 n2r[8]; load_w8(n2r, wt + N2_OFF, cwb, lr, lh);
    fv4 bb0 = *(const fv4*)(nb2 + cb0);
    fv4 bb1 = *(const fv4*)(nb2 + cb0 + 16);
    #pragma unroll
    for (int t = 0; t < 4; ++t) {
      fv4 acc0 = bb0, acc1 = bb1;
      #pragma unroll
      for (int ks = 0; ks < 4; ++ks) {
        bv8 b = *(const bv8*)(sN1 + swz8(t*16 + lr, ks*32 + lh*8));
        acc0 = MFMA(n2r[ks],   b, acc0);
        acc1 = MFMA(n2r[4+ks], b, acc1);
      }
      uint2 r0 = *(const uint2*)(sIn0 + swz8(t*16 + lr, cb0));
      uint2 r1 = *(const uint2*)(sIn0 + swz8(t*16 + lr, cb0 + 16));
      float v0 = b2f((unsigned short)(r0.x))       + acc0[0];
      float v1 = b2f((unsigned short)(r0.x >> 16)) + acc0[1];
      float v2 = b2f((unsigned short)(r0.y))       + acc0[2];
      float v3 = b2f((unsigned short)(r0.y >> 16)) + acc0[3];
      float w0 = b2f((unsigned short)(r1.x))       + acc1[0];
      float w1 = b2f((unsigned short)(r1.x >> 16)) + acc1[1];
      float w2 = b2f((unsigned short)(r1.y))       + acc1[2];
      float w3 = b2f((unsigned short)(r1.y >> 16)) + acc1[3];
      int g = (node0 + t*16 + lr)*HD + cb0;
      uint2 p;
      p.x = pk2(v0, v1); p.y = pk2(v2, v3);
      *(uint2*)(hhbout + g) = p;
      p.x = pk2(w0, w1); p.y = pk2(w2, w3);
      *(uint2*)(hhbout + g + 16) = p;
    }
  }
}

extern "C" void kernel_launch(void* const* d_in, const int* in_sizes, int n_in,
                              void* d_out, int out_size, void* d_ws, size_t ws_size,
                              hipStream_t stream)
{
  (void)in_sizes; (void)n_in; (void)out_size; (void)ws_size;
  const float* h   = (const float*)d_in[0];
  const int*   idx = (const int*)d_in[1];
  const float* eiw = (const float*)d_in[2];
  const float* eib = (const float*)d_in[3];
  const float* ew1 = (const float*)d_in[4];
  const float* eb1 = (const float*)d_in[5];
  const float* ew2 = (const float*)d_in[6];
  const float* eb2 = (const float*)d_in[7];
  const float* cw1 = (const float*)d_in[8];
  const float* cb1 = (const float*)d_in[9];
  const float* cw2 = (const float*)d_in[10];
  const float* nw1 = (const float*)d_in[11];
  const float* nb1 = (const float*)d_in[12];
  const float* nw2 = (const float*)d_in[13];
  const float* nb2 = (const float*)d_in[14];
  const float* eow = (const float*)d_in[15];
  const float* eob = (const float*)d_in[16];

  unsigned char* ws = (unsigned char*)d_ws;
  unsigned short* wt    = (unsigned short*)ws;                // 1,605,632 B
  unsigned short* hhbA  = (unsigned short*)(ws + 1605632);    // 4,194,304 B
  unsigned short* hhbB  = (unsigned short*)(ws + 5799936);    // 4,194,304 B
  float*          xA    = (float*)(ws + 9994240);             // 262,144 B
  float*          xB    = (float*)(ws + 10256384);            // 262,144 B
  unsigned short* aggg  = (unsigned short*)(ws + 10518528);   // 4,194,304 B
  float*          diffg = (float*)(ws + 14712832);            // 2,621,440 B
  float*          cmPg  = (float*)(ws + 17334272);            // 2,621,440 B

  prep_kernel<<<(NL*WL_STRIDE + 255)/256, 256, 0, stream>>>(ew1, ew2, cw1, nw1, nw2, wt);
  init_kernel<<<NN*HD/256, 256, 0, stream>>>(h, eiw, eib, hhbA, xA);

  unsigned short* hbs = hhbA; unsigned short* hbd = hhbB;
  float* xs = xA; float* xd = xB;
  for (int l = 0; l < NL; ++l) {
    edge_kernel<<<NN/TM, 256, 0, stream>>>(idx, wt + (size_t)l*WL_STRIDE,
        eb1 + l*128, eb2 + l*128, cb1 + l*128, cw2 + l*128,
        ew1 + (size_t)l*257*128,
        hbs, xs, aggg, diffg, cmPg);
    node_kernel<<<NN/64, 256, 0, stream>>>(wt + (size_t)l*WL_STRIDE,
        nb1 + l*128, nb2 + l*128,
        hbs, aggg, diffg, cmPg, xs, xd, hbd);
    unsigned short* ht = hbs; hbs = hbd; hbd = ht;
    float* t = xs; xs = xd; xd = t;
  }
  out_kernel<<<NN*4/256, 256, 0, stream>>>(hbs, xs, eow, eob, (float*)d_out);
}

// Round 17
// 388.817 us; speedup vs baseline: 1.9612x; 1.0388x over previous
//
#include <hip/hip_runtime.h>
#include <hip/hip_bf16.h>

#define NN 16384
#define KNN 10
#define HD 128
#define NL 7
#define TM 8
#define EDG 80      // TM*KNN
#define NE (NN*KNN) // total edges

// per-layer bf16 weight layout offsets (elements), all [outcol][k] (= W^T rows)
#define W1E_OFF 0
#define W1D_OFF 16384
#define W2_OFF  32768
#define C1_OFF  49152
#define N1_OFF  65536    // [outcol][256]
#define N2_OFF  98304
#define WL_STRIDE 114688

typedef float fv4 __attribute__((ext_vector_type(4)));
typedef short bv8 __attribute__((ext_vector_type(8)));

static __device__ __forceinline__ unsigned short f2b(float f) {
  __hip_bfloat16 h = __float2bfloat16(f);
  return __builtin_bit_cast(unsigned short, h);
}
static __device__ __forceinline__ float b2f(unsigned short u) {
  unsigned int x = ((unsigned int)u) << 16;
  return __builtin_bit_cast(float, x);
}
static __device__ __forceinline__ unsigned int pk2(float lo, float hi) {
  unsigned int r;
  asm("v_cvt_pk_bf16_f32 %0, %1, %2" : "=v"(r) : "v"(lo), "v"(hi));
  return r;
}
static __device__ __forceinline__ float silu_f(float x) {
  return x * __builtin_amdgcn_rcpf(1.0f + __expf(-x));
}
#define MFMA(a,b,c) __builtin_amdgcn_mfma_f32_16x16x32_bf16((a),(b),(c),0,0,0)

// direct global->LDS 16B DMA (dest = wave-uniform base + lane*16)
#define GLOAD_LDS(gp, lp) \
  __builtin_amdgcn_global_load_lds((const __attribute__((address_space(1))) void*)(gp), \
                                   (__attribute__((address_space(3))) void*)(lp), 16, 0, 0)

// activation LDS layout: [row][128 col] shorts, col XOR'd by (row&7)<<3
static __device__ __forceinline__ int swz8(int row, int col) {
  return row * 128 + (col ^ ((row & 7) << 3));
}

// ---------------- weight prep: fp32 -> bf16 transposed [outcol][k] ----------------
__global__ void prep_kernel(const float* __restrict__ ew1, const float* __restrict__ ew2,
                            const float* __restrict__ cw1, const float* __restrict__ nw1,
                            const float* __restrict__ nw2, unsigned short* __restrict__ wt)
{
  int g = blockIdx.x * 256 + threadIdx.x;
  if (g >= NL * WL_STRIDE) return;
  int l = g / WL_STRIDE;
  int r = g % WL_STRIDE;
  float v;
  if (r < 16384) {                       // W1e
    int c = r >> 7, k = r & 127;
    v = ew1[(l*257 + 1 + k)*128 + c];
  } else if (r < 32768) {                // W1d
    int q = r - 16384; int c = q >> 7, k = q & 127;
    v = ew1[(l*257 + 129 + k)*128 + c];
  } else if (r < 49152) {                // W2
    int q = r - 32768; int c = q >> 7, k = q & 127;
    v = ew2[(l*128 + k)*128 + c];
  } else if (r < 65536) {                // C1
    int q = r - 49152; int c = q >> 7, k = q & 127;
    v = cw1[(l*128 + k)*128 + c];
  } else if (r < 98304) {                // N1 [c][k0..255]
    int q = r - 65536; int c = q >> 8, k = q & 255;
    v = nw1[(l*256 + k)*128 + c];
  } else {                               // N2
    int q = r - 98304; int c = q >> 7, k = q & 127;
    v = nw2[(l*128 + k)*128 + c];
  }
  wt[g] = f2b(v);
}

// ---------------- embedding_in (bf16 hh) + x init ----------------
__global__ void init_kernel(const float* __restrict__ h, const float* __restrict__ eiw,
                            const float* __restrict__ eib,
                            unsigned short* __restrict__ hhb, float* __restrict__ x)
{
  int g = blockIdx.x * 256 + threadIdx.x;   // 16384*128
  int n = g >> 7, c = g & 127;
  float acc = eib[c];
  #pragma unroll
  for (int j = 0; j < 8; ++j) acc += h[n*11 + 3 + j] * eiw[j*128 + c];
  hhb[g] = f2b(acc);
  if (c < 3) x[n*4 + c] = h[n*11 + c] * (1.0f/3330.0f);
  if (c == 3) x[n*4 + 3] = 0.f;
}

// ---------------- embedding_out (vectorized bf16 reads) ----------------
__global__ void out_kernel(const unsigned short* __restrict__ hhb, const float* __restrict__ x,
                           const float* __restrict__ ow, const float* __restrict__ ob,
                           float* __restrict__ out)
{
  __shared__ float sOW[131*4];
  int tid = threadIdx.x;
  for (int i = tid; i < 131*4; i += 256) sOW[i] = ow[i];
  __syncthreads();
  int g = blockIdx.x * 256 + tid;           // 16384*4
  int n = g >> 2, o = g & 3;
  float acc = ob[o];
  #pragma unroll
  for (int kk = 0; kk < 16; ++kk) {
    bv8 v = *(const bv8*)(hhb + n*128 + kk*8);
    #pragma unroll
    for (int j = 0; j < 8; ++j)
      acc += b2f((unsigned short)v[j]) * sOW[(kk*8 + j)*4 + o];
  }
  #pragma unroll
  for (int d = 0; d < 3; ++d) acc += x[n*4 + d] * sOW[(128 + d)*4 + o];
  out[g] = acc;
}

// A-frag (weight) slices for this wave's 32 out-channels
static __device__ __forceinline__ void load_w8(bv8* w, const unsigned short* __restrict__ W,
                                               int cwb, int lr, int lh) {
  #pragma unroll
  for (int ks = 0; ks < 4; ++ks) {
    w[ks]     = *(const bv8*)(W + (cwb      + lr)*128 + ks*32 + lh*8);
    w[4 + ks] = *(const bv8*)(W + (cwb + 16 + lr)*128 + ks*32 + lh*8);
  }
}

// ---------------- edge kernel: gather + edge MLP + coord head, 3 barriers ----------------
__global__ __launch_bounds__(256, 3) void edge_kernel(
    const int* __restrict__ idxp,
    const unsigned short* __restrict__ wt,
    const float* __restrict__ eb1, const float* __restrict__ eb2,
    const float* __restrict__ cb1, const float* __restrict__ cw2,
    const float* __restrict__ w1r0p,
    const unsigned short* __restrict__ hhbin,
    const float* __restrict__ xin,
    unsigned short* __restrict__ aggg,   // [NN][128] bf16 sum_ef
    float* __restrict__ diffg,           // [NE][4]  (dx,dy,dz,rad)
    float* __restrict__ cmPg)            // [4][NE]  per-wave cm partials
{
  __shared__ __align__(16) unsigned char smem[45504];
  unsigned short* sA   = (unsigned short*)(smem);           // [80][128] hh_src -> ef
  unsigned short* sB   = (unsigned short*)(smem + 20480);   // [80][128] t1
  float*          sHC  = (float*)(smem + 40960);            // [8][132] fp32 hc
  float*          sRad = (float*)(smem + 45184);            // [80]
  unsigned short* sEf = sA;

  const int tid  = threadIdx.x;
  const int wave = tid >> 6;
  const int lane = tid & 63;
  const int lr   = lane & 15;
  const int lh   = lane >> 4;
  const int cwb  = wave * 32;
  const int cb0  = cwb + lh*4;
  const int node0 = blockIdx.x * TM;

  // ---- async gather hh_src -> sA (source-swizzled cols) ----
  #pragma unroll
  for (int it = 0; it < 5; ++it) {
    int q = tid + it*256;                 // 1280 = 80 rows x 16 chunks
    int e = q >> 4, cq = q & 15;
    int s = idxp[node0*KNN + e];
    int csw = (cq ^ (e & 7)) << 3;
    GLOAD_LDS(hhbin + s*HD + csw, sA + ((q & ~63) << 3));
  }

  // ---- early register loads ----
  bv8 hb[4];
  #pragma unroll
  for (int ks = 0; ks < 4; ++ks)
    hb[ks] = *(const bv8*)(hhbin + (node0 + (lr & 7))*HD + ks*32 + lh*8);
  bv8 wd[8]; load_w8(wd, wt + W1D_OFF, cwb, lr, lh);
  fv4 cw2v0 = *(const fv4*)(cw2 + cb0);
  fv4 cw2v1 = *(const fv4*)(cw2 + cb0 + 16);
  fv4 w1r0v0 = *(const fv4*)(w1r0p + cb0);
  fv4 w1r0v1 = *(const fv4*)(w1r0p + cb0 + 16);

  // ---- diff/radial fp32 (+ diff to global for node kernel) ----
  if (tid < EDG) {
    int e = tid, n = e / KNN;
    int s = idxp[node0*KNN + e];
    fv4 xs4 = *(const fv4*)(xin + s*4);
    fv4 xd4 = *(const fv4*)(xin + (node0+n)*4);
    float d0 = xs4[0]-xd4[0], d1 = xs4[1]-xd4[1], d2 = xs4[2]-xd4[2];
    float rad = d0*d0 + d1*d1 + d2*d2;
    sRad[e] = rad;
    fv4 dv = (fv4){d0, d1, d2, rad};
    *(fv4*)(diffg + (node0*KNN + e)*4) = dv;
  }
  // ---- hc = W1d^T @ hh_dst + b1 (registers only; pre-barrier) ----
  {
    fv4 hac0 = *(const fv4*)(eb1 + cb0);
    fv4 hac1 = *(const fv4*)(eb1 + cb0 + 16);
    #pragma unroll
    for (int ks = 0; ks < 4; ++ks) {
      hac0 = MFMA(wd[ks],   hb[ks], hac0);
      hac1 = MFMA(wd[4+ks], hb[ks], hac1);
    }
    if (lr < TM) {
      *(fv4*)(sHC + lr*132 + cb0)      = hac0;
      *(fv4*)(sHC + lr*132 + cb0 + 16) = hac1;
    }
  }
  bv8 we[8]; load_w8(we, wt + W1E_OFF, cwb, lr, lh);
  __syncthreads();                                      // B1 (drains gather DMA)

  // ---- G1: t1 = silu(W1e^T@hh_src + hc + rad*w1r0) -> sB ; prefetch W2 ----
  bv8 w2r[8]; load_w8(w2r, wt + W2_OFF, cwb, lr, lh);
  {
    fv4 acc[5][2];
    #pragma unroll
    for (int n = 0; n < 5; ++n) {
      int e = n*16 + lr;
      int nd = e / KNN;
      float rad = sRad[e];
      fv4 h0 = *(const fv4*)(sHC + nd*132 + cb0);
      fv4 h1 = *(const fv4*)(sHC + nd*132 + cb0 + 16);
      acc[n][0] = h0 + w1r0v0*rad;
      acc[n][1] = h1 + w1r0v1*rad;
    }
    #pragma unroll
    for (int ks = 0; ks < 4; ++ks) {
      #pragma unroll
      for (int n = 0; n < 5; ++n) {
        bv8 b = *(const bv8*)(sA + swz8(n*16 + lr, ks*32 + lh*8));
        acc[n][0] = MFMA(we[ks],   b, acc[n][0]);
        acc[n][1] = MFMA(we[4+ks], b, acc[n][1]);
      }
    }
    #pragma unroll
    for (int n = 0; n < 5; ++n) {
      int e = n*16 + lr;
      #pragma unroll
      for (int mt = 0; mt < 2; ++mt) {
        uint2 p;
        p.x = pk2(silu_f(acc[n][mt][0]), silu_f(acc[n][mt][1]));
        p.y = pk2(silu_f(acc[n][mt][2]), silu_f(acc[n][mt][3]));
        *(uint2*)(sB + swz8(e, cb0 + mt*16)) = p;
      }
    }
  }
  __syncthreads();                                      // B2

  // ---- G2: ef = silu(W2^T @ t1 + b2) -> sA ; prefetch C1 + cb1 ----
  bv8 c1r[8]; load_w8(c1r, wt + C1_OFF, cwb, lr, lh);
  fv4 c1b0 = *(const fv4*)(cb1 + cb0);
  fv4 c1b1 = *(const fv4*)(cb1 + cb0 + 16);
  {
    fv4 bb0 = *(const fv4*)(eb2 + cb0);
    fv4 bb1 = *(const fv4*)(eb2 + cb0 + 16);
    fv4 acc[5][2];
    #pragma unroll
    for (int n = 0; n < 5; ++n) { acc[n][0] = bb0; acc[n][1] = bb1; }
    #pragma unroll
    for (int ks = 0; ks < 4; ++ks) {
      #pragma unroll
      for (int n = 0; n < 5; ++n) {
        bv8 b = *(const bv8*)(sB + swz8(n*16 + lr, ks*32 + lh*8));
        acc[n][0] = MFMA(w2r[ks],   b, acc[n][0]);
        acc[n][1] = MFMA(w2r[4+ks], b, acc[n][1]);
      }
    }
    #pragma unroll
    for (int n = 0; n < 5; ++n) {
      int e = n*16 + lr;
      #pragma unroll
      for (int mt = 0; mt < 2; ++mt) {
        uint2 p;
        p.x = pk2(silu_f(acc[n][mt][0]), silu_f(acc[n][mt][1]));
        p.y = pk2(silu_f(acc[n][mt][2]), silu_f(acc[n][mt][3]));
        *(uint2*)(sA + swz8(e, cb0 + mt*16)) = p;
      }
    }
  }
  __syncthreads();                                      // B3

  // ---- G3: c1 in-register; cm partials -> cmPg; sum_ef on ALL threads -> aggg ----
  {
    fv4 acc[5][2];
    #pragma unroll
    for (int n = 0; n < 5; ++n) { acc[n][0] = c1b0; acc[n][1] = c1b1; }
    #pragma unroll
    for (int ks = 0; ks < 4; ++ks) {
      #pragma unroll
      for (int n = 0; n < 5; ++n) {
        bv8 b = *(const bv8*)(sEf + swz8(n*16 + lr, ks*32 + lh*8));
        acc[n][0] = MFMA(c1r[ks],   b, acc[n][0]);
        acc[n][1] = MFMA(c1r[4+ks], b, acc[n][1]);
      }
    }
    // cm partials: silu + dot vs cw2 (fp32), reduce across lh, store per-wave
    #pragma unroll
    for (int n = 0; n < 5; ++n) {
      float pm = 0.f;
      #pragma unroll
      for (int j = 0; j < 4; ++j) {
        pm += silu_f(acc[n][0][j]) * cw2v0[j];
        pm += silu_f(acc[n][1][j]) * cw2v1[j];
      }
      pm += __shfl_xor(pm, 16);
      pm += __shfl_xor(pm, 32);
      if (lane < 16) cmPg[wave*NE + node0*KNN + n*16 + lr] = pm;
    }
    // sum_ef rebalanced across all 256 threads: each does 4 cols of one node
    {
      int n = tid >> 5, c = (tid & 31) << 2;
      float s0 = 0.f, s1 = 0.f, s2 = 0.f, s3 = 0.f;
      #pragma unroll
      for (int k = 0; k < KNN; ++k) {
        ushort4 v = *(const ushort4*)(sEf + swz8(n*KNN + k, c));
        s0 += b2f(v.x); s1 += b2f(v.y); s2 += b2f(v.z); s3 += b2f(v.w);
      }
      uint2 pv;
      pv.x = pk2(s0, s1);
      pv.y = pk2(s2, s3);
      *(uint2*)(aggg + (node0 + n)*HD + c) = pv;
    }
  }
}

// ---------------- node kernel: x-update + node MLP over 64 nodes/block ----------------
__global__ __launch_bounds__(256, 3) void node_kernel(
    const unsigned short* __restrict__ wt,
    const float* __restrict__ nb1, const float* __restrict__ nb2,
    const unsigned short* __restrict__ hhbin,
    const unsigned short* __restrict__ aggg,
    const float* __restrict__ diffg,
    const float* __restrict__ cmPg,
    const float* __restrict__ xin, float* __restrict__ xout,
    unsigned short* __restrict__ hhbout)
{
  __shared__ __align__(16) unsigned char smem[49152];
  unsigned short* sIn0 = (unsigned short*)(smem);           // [64][128] hh
  unsigned short* sIn1 = (unsigned short*)(smem + 16384);   // [64][128] sum_ef
  unsigned short* sN1  = (unsigned short*)(smem + 32768);   // [64][128] n1

  const int tid  = threadIdx.x;
  const int lane = tid & 63;
  const int wave = tid >> 6;
  const int lr   = lane & 15;
  const int lh   = lane >> 4;
  const int cwb  = wave * 32;
  const int cb0  = cwb + lh*4;
  const int node0 = blockIdx.x * 64;

  // ---- stage hh + sum_ef -> LDS via DMA (source-swizzled cols) ----
  #pragma unroll
  for (int it = 0; it < 4; ++it) {
    int q = tid + it*256;                 // 1024 = 64 rows x 16 chunks
    int r = q >> 4, cq = q & 15;
    int csw = (cq ^ (r & 7)) << 3;
    GLOAD_LDS(hhbin + (node0 + r)*HD + csw, sIn0 + ((q & ~63) << 3));
  }
  #pragma unroll
  for (int it = 0; it < 4; ++it) {
    int q = tid + it*256;
    int r = q >> 4, cq = q & 15;
    int csw = (cq ^ (r & 7)) << 3;
    GLOAD_LDS(aggg + (node0 + r)*HD + csw, sIn1 + ((q & ~63) << 3));
  }
  // ---- N1 weight prefetch (overlaps DMA) ----
  bv8 n1r[16];
  #pragma unroll
  for (int ks = 0; ks < 8; ++ks) {
    n1r[ks]     = *(const bv8*)(wt + N1_OFF + (cwb      + lr)*256 + ks*32 + lh*8);
    n1r[8 + ks] = *(const bv8*)(wt + N1_OFF + (cwb + 16 + lr)*256 + ks*32 + lh*8);
  }
  // ---- x-update (overlaps DMA; pure global reads) ----
  if (tid < 192) {
    int n = tid / 3, d = tid % 3;
    int e0 = (node0 + n)*KNN;
    float xo = xin[(node0+n)*4 + d];
    xo = fminf(fmaxf(xo, -1000.f), 1000.f);
    float s = 0.f;
    #pragma unroll
    for (int k = 0; k < KNN; ++k) {
      int e = e0 + k;
      float cm = cmPg[e] + cmPg[NE + e] + cmPg[2*NE + e] + cmPg[3*NE + e];
      float tr = diffg[e*4 + d] * cm;
      tr = fminf(fmaxf(tr, -1000.f), 1000.f);
      s += tr;
    }
    xout[(node0+n)*4 + d] = xo + s * (1.0f/KNN);
  }
  __syncthreads();                                      // B1 (drains DMA)

  // ---- nG1: n1 = silu(N1^T @ [hh | sum_ef] + nb1) -> sN1 ----
  {
    fv4 bb0 = *(const fv4*)(nb1 + cb0);
    fv4 bb1 = *(const fv4*)(nb1 + cb0 + 16);
    #pragma unroll
    for (int t = 0; t < 4; ++t) {
      fv4 acc0 = bb0, acc1 = bb1;
      #pragma unroll
      for (int ks = 0; ks < 4; ++ks) {
        bv8 b0 = *(const bv8*)(sIn0 + swz8(t*16 + lr, ks*32 + lh*8));
        bv8 b1 = *(const bv8*)(sIn1 + swz8(t*16 + lr, ks*32 + lh*8));
        acc0 = MFMA(n1r[ks],      b0, acc0);
        acc0 = MFMA(n1r[4+ks],    b1, acc0);
        acc1 = MFMA(n1r[8+ks],    b0, acc1);
        acc1 = MFMA(n1r[12+ks],   b1, acc1);
      }
      uint2 p0, p1;
      p0.x = pk2(silu_f(acc0[0]), silu_f(acc0[1]));
      p0.y = pk2(silu_f(acc0[2]), silu_f(acc0[3]));
      p1.x = pk2(silu_f(acc1[0]), silu_f(acc1[1]));
      p1.y = pk2(silu_f(acc1[2]), silu_f(acc1[3]));
      *(uint2*)(sN1 + swz8(t*16 + lr, cb0))      = p0;
      *(uint2*)(sN1 + swz8(t*16 + lr, cb0 + 16)) = p1;
    }
  }
  __syncthreads();                                      // B2

  // ---- nG2: hh_out = hh + N2^T @ n1 + nb2 -> hhbout ----
  {
    bv8 n2r[8]; load_w8(n2r, wt + N2_OFF, cwb, lr, lh);
    fv4 bb0 = *(const fv4*)(nb2 + cb0);
    fv4 bb1 = *(const fv4*)(nb2 + cb0 + 16);
    #pragma unroll
    for (int t = 0; t < 4; ++t) {
      fv4 acc0 = bb0, acc1 = bb1;
      #pragma unroll
      for (int ks = 0; ks < 4; ++ks) {
        bv8 b = *(const bv8*)(sN1 + swz8(t*16 + lr, ks*32 + lh*8));
        acc0 = MFMA(n2r[ks],   b, acc0);
        acc1 = MFMA(n2r[4+ks], b, acc1);
      }
      uint2 r0 = *(const uint2*)(sIn0 + swz8(t*16 + lr, cb0));
      uint2 r1 = *(const uint2*)(sIn0 + swz8(t*16 + lr, cb0 + 16));
      float v0 = b2f((unsigned short)(r0.x))       + acc0[0];
      float v1 = b2f((unsigned short)(r0.x >> 16)) + acc0[1];
      float v2 = b2f((unsigned short)(r0.y))       + acc0[2];
      float v3 = b2f((unsigned short)(r0.y >> 16)) + acc0[3];
      float w0 = b2f((unsigned short)(r1.x))       + acc1[0];
      float w1 = b2f((unsigned short)(r1.x >> 16)) + acc1[1];
      float w2 = b2f((unsigned short)(r1.y))       + acc1[2];
      float w3 = b2f((unsigned short)(r1.y >> 16)) + acc1[3];
      int g = (node0 + t*16 + lr)*HD + cb0;
      uint2 p;
      p.x = pk2(v0, v1); p.y = pk2(v2, v3);
      *(uint2*)(hhbout + g) = p;
      p.x = pk2(w0, w1); p.y = pk2(w2, w3);
      *(uint2*)(hhbout + g + 16) = p;
    }
  }
}

extern "C" void kernel_launch(void* const* d_in, const int* in_sizes, int n_in,
                              void* d_out, int out_size, void* d_ws, size_t ws_size,
                              hipStream_t stream)
{
  (void)in_sizes; (void)n_in; (void)out_size; (void)ws_size;
  const float* h   = (const float*)d_in[0];
  const int*   idx = (const int*)d_in[1];
  const float* eiw = (const float*)d_in[2];
  const float* eib = (const float*)d_in[3];
  const float* ew1 = (const float*)d_in[4];
  const float* eb1 = (const float*)d_in[5];
  const float* ew2 = (const float*)d_in[6];
  const float* eb2 = (const float*)d_in[7];
  const float* cw1 = (const float*)d_in[8];
  const float* cb1 = (const float*)d_in[9];
  const float* cw2 = (const float*)d_in[10];
  const float* nw1 = (const float*)d_in[11];
  const float* nb1 = (const float*)d_in[12];
  const float* nw2 = (const float*)d_in[13];
  const float* nb2 = (const float*)d_in[14];
  const float* eow = (const float*)d_in[15];
  const float* eob = (const float*)d_in[16];

  unsigned char* ws = (unsigned char*)d_ws;
  unsigned short* wt    = (unsigned short*)ws;                // 1,605,632 B
  unsigned short* hhbA  = (unsigned short*)(ws + 1605632);    // 4,194,304 B
  unsigned short* hhbB  = (unsigned short*)(ws + 5799936);    // 4,194,304 B
  float*          xA    = (float*)(ws + 9994240);             // 262,144 B
  float*          xB    = (float*)(ws + 10256384);            // 262,144 B
  unsigned short* aggg  = (unsigned short*)(ws + 10518528);   // 4,194,304 B
  float*          diffg = (float*)(ws + 14712832);            // 2,621,440 B
  float*          cmPg  = (float*)(ws + 17334272);            // 2,621,440 B

  prep_kernel<<<(NL*WL_STRIDE + 255)/256, 256, 0, stream>>>(ew1, ew2, cw1, nw1, nw2, wt);
  init_kernel<<<NN*HD/256, 256, 0, stream>>>(h, eiw, eib, hhbA, xA);

  unsigned short* hbs = hhbA; unsigned short* hbd = hhbB;
  float* xs = xA; float* xd = xB;
  for (int l = 0; l < NL; ++l) {
    edge_kernel<<<NN/TM, 256, 0, stream>>>(idx, wt + (size_t)l*WL_STRIDE,
        eb1 + l*128, eb2 + l*128, cb1 + l*128, cw2 + l*128,
        ew1 + (size_t)l*257*128,
        hbs, xs, aggg, diffg, cmPg);
    node_kernel<<<NN/64, 256, 0, stream>>>(wt + (size_t)l*WL_STRIDE,
        nb1 + l*128, nb2 + l*128,
        hbs, aggg, diffg, cmPg, xs, xd, hbd);
    unsigned short* ht = hbs; hbs = hbd; hbd = ht;
    float* t = xs; xs = xd; xd = t;
  }
  out_kernel<<<NN*4/256, 256, 0, stream>>>(hbs, xs, eow, eob, (float*)d_out);
}